// Round 9
// baseline (297.110 us; speedup 1.0000x reference)
//
#include <hip/hip_runtime.h>

// SJLT projection: out[b, idx[d,j]] += x[b,d] * sign(d,j), * 1/sqrt(4)
// B=64, D=524288, P=8192, C=4.
//
// Model so far (R1-R14):
//  - Random 4B global stores: 64B HBM write-back EACH. L2 no-write-allocate;
//    pretouch (R9) and spatial partitioning (R8) do NOT help. Only LDS-staged
//    coalesced chunk writes avoid the ~10x inflation.
//  - Harness re-poisons the full ws INSIDE the timed region: fillBuffer
//    = 82 us/iter. Floor ~= 82 + launches + our kernels.
//  - SQ_LDS_BANK_CONFLICT does NOT correlate with duration -- stop chasing.
//  - Fine-bin/pre-sort in gather is pure loss; direct-stream + register
//    accumulators + wave-uniform switch routing wins (gather9 <81us, R14).
//  - R14 = 295.9: fill 82 + prep 81.3 + gather9(<81) + memset + gaps.
//    prep at VALUBusy 12%, HBM 24% -> latency/sync-bound: per-iter global
//    load inside the loop + 2 syncs x 4 iters expose ~600cy latency 4x.
// R15: pipeline the transpose in prep: prefetch all 4 float4 loads at
// block start (4x MLP, latency exposed once) + LDS double-buffer (33 KB,
// fits 41 KB union) -> 1 sync/iter instead of 2. binA + gather9 unchanged.

constexpr int BATCH = 64;
constexpr int DIM   = 524288;
constexpr int PROJ  = 8192;
constexpr int NENT  = DIM * 4;          // 2,097,152 entries
constexpr int NBLKA = 256;              // binA blocks
constexpr int EPB   = NENT / NBLKA;     // 8192 entries per binA block
constexpr int NHB   = 512;              // half-buckets
constexpr int HBP   = PROJ / NHB;       // 16 p per half-bucket
constexpr int CAPH  = 4608;             // dense cap per hb: mean 4096 + 8 sigma
constexpr int TBLK  = 2048;             // transpose blocks (256 d each)

// ------------------------------------------------ helpers
__device__ __forceinline__ uint32_t f2bf(float f) {   // RNE f32 -> bf16 bits
    uint32_t u = __float_as_uint(f);
    return (u + 0x7fffu + ((u >> 16) & 1u)) >> 16;
}

// ==================== pass 1: fused binA + transpose ====================
// Blocks [0,256): binA (unchanged, proven R13/R14).
// Blocks [256,2304): transpose, now pipelined: 4 prefetched loads + LDS
// double-buffer + single sync per tile iteration.
__global__ __launch_bounds__(1024) void prep_kernel(
    const float* __restrict__ x, const int4* __restrict__ idx4,
    const int4* __restrict__ sgn4, uint32_t* __restrict__ gBase,
    uint32_t* __restrict__ dense, uint32_t* __restrict__ xT)
{
    __shared__ uint32_t sh[10260];       // 41,040 B, unioned
    const int t = threadIdx.x;

    if (blockIdx.x < NBLKA) {
        // ---------------- binA (unchanged) ----------------
        uint32_t* cntL    = sh;          // 512
        uint32_t* offL    = sh + 512;    // 512
        uint32_t* curL    = sh + 1024;   // 512
        uint32_t* wsum    = sh + 1536;   // 8
        uint32_t* gb      = sh + 1544;   // 512
        uint32_t* staging = sh + 2056;   // 8192 (32 KB)
        const int lane = t & 63;
        const int blk  = blockIdx.x;

        if (t < NHB) cntL[t] = 0;
        __syncthreads();

        int4 iv[2], sv[2];
        int  dd[2];
#pragma unroll
        for (int j = 0; j < 2; ++j) {
            int d = blk * 2048 + j * 1024 + t;
            dd[j] = d;
            iv[j] = idx4[d];
            sv[j] = sgn4[d];
        }
#pragma unroll
        for (int j = 0; j < 2; ++j) {
            atomicAdd(&cntL[(uint32_t)iv[j].x >> 4], 1u);
            atomicAdd(&cntL[(uint32_t)iv[j].y >> 4], 1u);
            atomicAdd(&cntL[(uint32_t)iv[j].z >> 4], 1u);
            atomicAdd(&cntL[(uint32_t)iv[j].w >> 4], 1u);
        }
        __syncthreads();
        // exclusive scan of cntL[512] (first 8 waves)
        uint32_t v = 0, s = 0;
        if (t < NHB) {
            s = cntL[t]; v = s;
#pragma unroll
            for (int off = 1; off < 64; off <<= 1) {
                uint32_t u = __shfl_up(v, off);
                if (lane >= off) v += u;
            }
            if (lane == 63) wsum[t >> 6] = v;
        }
        __syncthreads();
        if (t < NHB) {
            uint32_t wb = 0;
            for (int w0 = 0; w0 < (t >> 6); ++w0) wb += wsum[w0];
            uint32_t ex = wb + v - s;
            offL[t] = ex;
            curL[t] = ex;
        }
        __syncthreads();
#pragma unroll
        for (int j = 0; j < 2; ++j) {
            const uint32_t dv = (uint32_t)dd[j] << 1;
            int p, ss;
            uint32_t b, sl;
            p = iv[j].x; ss = sv[j].x & 1; b = (uint32_t)p >> 4;
            sl = atomicAdd(&curL[b], 1u);
            staging[sl] = ((uint32_t)(p & 15) << 20) | dv | (uint32_t)ss;
            p = iv[j].y; ss = sv[j].y & 1; b = (uint32_t)p >> 4;
            sl = atomicAdd(&curL[b], 1u);
            staging[sl] = ((uint32_t)(p & 15) << 20) | dv | (uint32_t)ss;
            p = iv[j].z; ss = sv[j].z & 1; b = (uint32_t)p >> 4;
            sl = atomicAdd(&curL[b], 1u);
            staging[sl] = ((uint32_t)(p & 15) << 20) | dv | (uint32_t)ss;
            p = iv[j].w; ss = sv[j].w & 1; b = (uint32_t)p >> 4;
            sl = atomicAdd(&curL[b], 1u);
            staging[sl] = ((uint32_t)(p & 15) << 20) | dv | (uint32_t)ss;
        }
        __syncthreads();
        // global dense base per half-bucket (device-scope atomic)
        if (t < NHB) gb[t] = atomicAdd(&gBase[t], cntL[t]);
        __syncthreads();
        // append groups densely: wave w copies its 32 half-buckets
        const int w = t >> 6;
        for (int i = 0; i < NHB / 16; ++i) {
            const int b = w * (NHB / 16) + i;
            const uint32_t c   = cntL[b];
            const uint32_t src = offL[b];
            const uint32_t g0  = gb[b];
            const uint32_t lim = (g0 < (uint32_t)CAPH) ? ((uint32_t)CAPH - g0) : 0u;
            const uint32_t cw  = c < lim ? c : lim;
            uint32_t* dst = dense + (size_t)b * CAPH + g0;
            for (uint32_t j2 = lane; j2 < cw; j2 += 64) dst[j2] = staging[src + j2];
        }
    } else {
        // ------- transpose: 256 d per block, pipelined (R15) -------
        float* tile = reinterpret_cast<float*>(sh);   // 2 x [64][65] = 8320 f32
        const int blk   = blockIdx.x - NBLKA;         // 0..2047
        const int dbase = blk * 256;
        const int c  = t & 15;                        // float4 column
        const int r  = t >> 4;                        // batch row 0..63
        const int a  = t & 15;                        // uint2 column (of 16)
        const int dr = t >> 4;                        // d row 0..63

        // prefetch all 4 tiles' loads upfront: latency exposed once
        float4 v[4];
#pragma unroll
        for (int it = 0; it < 4; ++it) {
            v[it] = *reinterpret_cast<const float4*>(
                &x[(size_t)r * DIM + dbase + it * 64 + 4 * c]);
        }
#pragma unroll
        for (int it = 0; it < 4; ++it) {
            float* tb = tile + (it & 1) * 4160;       // double buffer
            tb[r * 65 + 4 * c + 0] = v[it].x;
            tb[r * 65 + 4 * c + 1] = v[it].y;
            tb[r * 65 + 4 * c + 2] = v[it].z;
            tb[r * 65 + 4 * c + 3] = v[it].w;
            __syncthreads();                          // one sync per iter
            const int d0 = dbase + it * 64;
            uint32_t lo, hi;
            lo = f2bf(tb[(4 * a + 0) * 65 + dr] * 0.5f);
            hi = f2bf(tb[(4 * a + 1) * 65 + dr] * 0.5f);
            const uint32_t w0 = lo | (hi << 16);
            lo = f2bf(tb[(4 * a + 2) * 65 + dr] * 0.5f);
            hi = f2bf(tb[(4 * a + 3) * 65 + dr] * 0.5f);
            const uint32_t w1 = lo | (hi << 16);
            uint2 wv; wv.x = w0; wv.y = w1;
            *reinterpret_cast<uint2*>(&xT[(size_t)(d0 + dr) * 32 + 2 * a]) = wv;
            // no trailing sync: next iter writes the other buffer; writes
            // to THIS buffer (it+2) are ordered after the it+1 sync, by
            // which time all waves have finished this iter's reads.
        }
    }
}

// ==================== pass 2: direct-stream gather (R14, proven) ========
#define G9_CASE(Q) case Q: acc0[Q] += v0; acc1[Q] += v1; break;
#define G9_SWITCH(PV)                                                     \
    switch (PV) {                                                         \
        G9_CASE(0)  G9_CASE(1)  G9_CASE(2)  G9_CASE(3)                    \
        G9_CASE(4)  G9_CASE(5)  G9_CASE(6)  G9_CASE(7)                    \
        G9_CASE(8)  G9_CASE(9)  G9_CASE(10) G9_CASE(11)                   \
        G9_CASE(12) G9_CASE(13) G9_CASE(14) G9_CASE(15)                   \
        default: break;                                                   \
    }

__global__ __launch_bounds__(1024) void gather9_kernel(
    const uint32_t* __restrict__ dense, const uint32_t* __restrict__ gBase,
    const uint32_t* __restrict__ xT, float* __restrict__ out)
{
    __shared__ float2 red2[8 * 528];         // 8 surfaces x 16q x 33 = 33,792 B
    const int t    = threadIdx.x;
    const int w    = t >> 6;                 // 0..15
    const int lane = t & 63;
    const int k    = lane & 31;              // u32 index in xT row (2 b's)
    const int hb   = blockIdx.x;             // half-bucket 0..511

    uint32_t nt = gBase[hb];
    if (nt > (uint32_t)CAPH) nt = (uint32_t)CAPH;
    const uint32_t* seg = dense + (size_t)hb * CAPH;
    const uint32_t s0 = (nt * (uint32_t)w) >> 4;
    const uint32_t s1 = (nt * (uint32_t)(w + 1)) >> 4;

    float acc0[16], acc1[16];
#pragma unroll
    for (int q = 0; q < 16; ++q) { acc0[q] = 0.f; acc1[q] = 0.f; }

    uint32_t base = s0;
    for (; base + 8 <= s1; base += 8) {
        uint32_t e8[8];
#pragma unroll
        for (int j = 0; j < 8; ++j) e8[j] = seg[base + j];     // uniform
        uint32_t u8[8];
#pragma unroll
        for (int j = 0; j < 8; ++j)                            // 8 in flight
            u8[j] = xT[(size_t)((e8[j] >> 1) & 0x7FFFFu) * 32 + k];
#pragma unroll
        for (int j = 0; j < 8; ++j) {
            const uint32_t u = u8[j] ^ ((e8[j] & 1u) ? 0u : 0x80008000u);
            const float v0 = __uint_as_float(u << 16);         // b = 2k
            const float v1 = __uint_as_float(u & 0xffff0000u); // b = 2k+1
            const int pv = __builtin_amdgcn_readfirstlane((int)((e8[j] >> 20) & 15u));
            G9_SWITCH(pv)
        }
    }
    for (; base < s1; ++base) {              // tail (<8 entries)
        const uint32_t e = seg[base];
        uint32_t u = xT[(size_t)((e >> 1) & 0x7FFFFu) * 32 + k];
        u ^= (e & 1u) ? 0u : 0x80008000u;
        const float v0 = __uint_as_float(u << 16);
        const float v1 = __uint_as_float(u & 0xffff0000u);
        const int pv = __builtin_amdgcn_readfirstlane((int)((e >> 20) & 15u));
        G9_SWITCH(pv)
    }

    // ---- tree reduce across 16 waves (lanes 0..31 carry the data) ----
#pragma unroll
    for (int stride = 8; stride >= 1; stride >>= 1) {
        if (w >= stride && w < 2 * stride && lane < 32) {
            float2* dst = red2 + (w - stride) * 528;
#pragma unroll
            for (int q = 0; q < 16; ++q)
                dst[q * 33 + k] = make_float2(acc0[q], acc1[q]);
        }
        __syncthreads();
        if (w < stride && lane < 32) {
            const float2* src = red2 + w * 528;
#pragma unroll
            for (int q = 0; q < 16; ++q) {
                float2 v = src[q * 33 + k];
                acc0[q] += v.x; acc1[q] += v.y;
            }
        }
        __syncthreads();
    }
    if (w == 0 && lane < 32) {
#pragma unroll
        for (int q = 0; q < 16; ++q)
            red2[q * 33 + k] = make_float2(acc0[q], acc1[q]);
    }
    __syncthreads();
    // out: thread t -> (b = t>>4, q = t&15); 16 consecutive q = 64B line
    {
        const int b = t >> 4, q = t & 15;
        const float2 vq = red2[q * 33 + (b >> 1)];
        out[(size_t)b * PROJ + hb * HBP + q] = (b & 1) ? vq.y : vq.x;
    }
}

// ------------------------------------------------- fallback (R3 scatter)
__device__ __forceinline__ void lds_fadd(uint32_t byte_addr, float v) {
    asm volatile("ds_add_f32 %0, %1" :: "v"(byte_addr), "v"(v) : "memory");
}
__device__ __forceinline__ void lds_fadd_off32k(uint32_t byte_addr, float v) {
    asm volatile("ds_add_f32 %0, %1 offset:32768" :: "v"(byte_addr), "v"(v) : "memory");
}

__global__ __launch_bounds__(1024) void sjlt_scatter(
    const float* __restrict__ x, const int4* __restrict__ idx4,
    const int4* __restrict__ sgn4, float* __restrict__ out)
{
    __shared__ float acc[4 * PROJ];
    for (int i = threadIdx.x; i < 4 * PROJ; i += 1024) acc[i] = 0.0f;
    __syncthreads();
    const int row0 = blockIdx.y * 4;
    const int dbeg = blockIdx.x * (DIM / 16);
    const uint32_t accBase = (uint32_t)(uintptr_t)(&acc[0]);
    const float* xr0 = x + (size_t)(row0 + 0) * DIM;
    const float* xr1 = x + (size_t)(row0 + 1) * DIM;
    const float* xr2 = x + (size_t)(row0 + 2) * DIM;
    const float* xr3 = x + (size_t)(row0 + 3) * DIM;
    for (int d = dbeg + (int)threadIdx.x; d < dbeg + DIM / 16; d += 1024) {
        const int4 iv = idx4[d];
        const int4 sv = sgn4[d];
        const uint32_t u0 = __float_as_uint(xr0[d]);
        const uint32_t u1 = __float_as_uint(xr1[d]);
        const uint32_t u2 = __float_as_uint(xr2[d]);
        const uint32_t u3 = __float_as_uint(xr3[d]);
        const int p[4] = {iv.x, iv.y, iv.z, iv.w};
        const int s[4] = {sv.x, sv.y, sv.z, sv.w};
#pragma unroll
        for (int j = 0; j < 4; ++j) {
            const uint32_t flip = (uint32_t)(s[j] ^ 1) << 31;
            const uint32_t a01  = accBase + ((uint32_t)p[j] << 2);
            const uint32_t a23  = a01 + 2u * 32768u;
            lds_fadd        (a01, __uint_as_float(u0 ^ flip));
            lds_fadd_off32k (a01, __uint_as_float(u1 ^ flip));
            lds_fadd        (a23, __uint_as_float(u2 ^ flip));
            lds_fadd_off32k (a23, __uint_as_float(u3 ^ flip));
        }
    }
    __syncthreads();
    for (int i = threadIdx.x; i < 4 * PROJ; i += 1024) {
        const int r  = i >> 13;
        const int pp = i & (PROJ - 1);
        unsafeAtomicAdd(&out[(size_t)(row0 + r) * PROJ + pp], acc[i] * 0.5f);
    }
}

// --------------------------------------------------------------- launch
extern "C" void kernel_launch(void* const* d_in, const int* in_sizes, int n_in,
                              void* d_out, int out_size, void* d_ws, size_t ws_size,
                              hipStream_t stream) {
    const float* x   = (const float*)d_in[0];
    const int4*  idx = (const int4*) d_in[1];
    const int4*  sgn = (const int4*) d_in[2];
    float*       out = (float*)d_out;

    // R15 layout: gBase[512] | dense[512*4608] | xT[DIM*32] = 76,548,096 B
    const size_t need = ((size_t)NHB + (size_t)NHB * CAPH + (size_t)DIM * 32) * 4;

    if (ws_size >= need) {
        uint32_t* gBase = (uint32_t*)d_ws;
        uint32_t* dense = gBase + NHB;
        uint32_t* xT    = dense + (size_t)NHB * CAPH;

        hipMemsetAsync(gBase, 0, NHB * sizeof(uint32_t), stream);  // 2 KB
        prep_kernel   <<<NBLKA + TBLK, 1024, 0, stream>>>(
            x, idx, sgn, gBase, dense, xT);
        gather9_kernel<<<NHB,          1024, 0, stream>>>(dense, gBase, xT, out);
    } else {
        // ws too small: R3 LDS-scatter path (passes at ~830 us)
        hipMemsetAsync(d_out, 0, (size_t)out_size * sizeof(float), stream);
        dim3 grid(16, 16);
        sjlt_scatter<<<grid, 1024, 0, stream>>>(x, idx, sgn, out);
    }
}